// Round 11
// baseline (166.295 us; speedup 1.0000x reference)
//
#include <hip/hip_runtime.h>

typedef short short8 __attribute__((ext_vector_type(8)));
typedef __bf16 bf16x8 __attribute__((ext_vector_type(8)));
typedef float floatx4 __attribute__((ext_vector_type(4)));

__device__ __forceinline__ float make_pow2(int e) {
  return __builtin_bit_cast(float, (unsigned)((e + 127) << 23));
}

// Raw barrier: drains LDS ops only (global loads are all to-register; ordinary
// register dependencies handle their waits).
__device__ __forceinline__ void barrier_lgkm() {
  asm volatile("s_waitcnt lgkmcnt(0)" ::: "memory");
  __builtin_amdgcn_sched_barrier(0);
  __builtin_amdgcn_s_barrier();
  asm volatile("" ::: "memory");
  __builtin_amdgcn_sched_barrier(0);
}

// ---------------- Phase 1: quantize weights -> bf16 FRAGMENT-ORDER blob ----------------
// Blob layout: [ct(16)][kb(18)][ks(2)][lane(64)][j(8)] bf16 = mfma src0 frag order.
__global__ void quant_w_kernel(const float* __restrict__ w, unsigned short* __restrict__ qw) {
  int b = blockIdx.x;                 // 0..287
  int ct = b / 18, kb = b - ct * 18;
  int L = threadIdx.x;                // 0..63
  int co = ct * 16 + (L & 15);
  int kq = L >> 4;                    // 0..3
  const float* wr = w + co * 1152 + kb * 64 + kq * 8;
  float v[16];
  float a = 0.f;
  #pragma unroll
  for (int ks = 0; ks < 2; ++ks)
    #pragma unroll
    for (int j = 0; j < 8; ++j) {
      float t = wr[ks * 32 + j];
      v[ks * 8 + j] = t;
      a = fmaxf(a, fabsf(t));
    }
  a = fmaxf(a, __shfl_xor(a, 16));
  a = fmaxf(a, __shfl_xor(a, 32));
  short8 q0 = (short8)0, q1 = (short8)0;
  if (a > 0.f) {
    int e = (int)((__builtin_bit_cast(unsigned, a) >> 23) & 0xffu) - 127;
    if (e < -126) e = -126;
    float inv = make_pow2(6 - e);
    float s   = make_pow2(e - 6);
    #pragma unroll
    for (int u = 0; u < 16; ++u) {
      float r = rintf(v[u] * inv);
      r = fminf(fmaxf(r, -128.f), 127.f);
      float qq = r * s;
      unsigned short hb = (unsigned short)(__builtin_bit_cast(unsigned, qq) >> 16);
      if (u < 8) q0[u] = (short)hb; else q1[u - 8] = (short)hb;
    }
  }
  unsigned short* dst = qw + (size_t)(ct * 18 + kb) * 1024;
  *(short8*)(dst + L * 8) = q0;          // ks = 0
  *(short8*)(dst + 512 + L * 8) = q1;    // ks = 1
}

// ---------------- Phase 2: fused im2col + BFP-quantize + GEMM ----------------
// M=100352, N=256, K=1152. BM=64, BN=256. 512 thr = 8 waves in a 2x4 grid:
// wm=wave>>2 (rows wm*32..+31), wn=wave&3 (cols wn*64..+63), acc[2][4].
// A-quantize is IN-WAVE: wave gathers all 64 k of rows wave*8..+7
// (row = wave*8 + lane>>3, k-slice = (lane&7)*8); per-row max via 3 shfl_xor;
// no pmax LDS, no cross-wave reduce. As rotates over 3 superphase slots x 2 kb.
// One lgkm barrier per 2-kb superphase.
__global__ __launch_bounds__(512, 4) void conv_bfp_kernel(
    const float* __restrict__ in, const unsigned short* __restrict__ qw,
    const float* __restrict__ bias, float* __restrict__ out) {
  __shared__ unsigned short As[3][2][64 * 64];   // 48 KB: [superphase%3][kb&1][m][k]

  const int bid = blockIdx.x;
  const int mt = (bid & 7) * 196 + (bid >> 3);   // XCD-chunked swizzle (1568 = 8*196)
  const int t = threadIdx.x;
  const int lane = t & 63;
  const int wave = __builtin_amdgcn_readfirstlane(t >> 6);
  const int wm = wave >> 2;                      // M-half 0/1 (rows wm*32..)
  const int wn = wave & 3;                       // N-quarter (cols wn*64..)

  // ---- producer-row geometry (row prow = wave*8 + lane>>3) ----
  const int prow = wave * 8 + (lane >> 3);
  const int q8 = (lane & 7) * 8;                 // k-slice base within the 64-block
  const unsigned m = mt * 64u + prow;
  const unsigned nimg = m / 3136u;
  const unsigned py = m - nimg * 3136u;
  const int y = (int)(py / 56u);
  const int x = (int)(py - (unsigned)y * 56u);
  const int eidx0 = (int)(nimg * 401408u + (unsigned)y * 56u + (unsigned)x);
  int vm = 0;
  #pragma unroll
  for (int i = 0; i < 3; ++i)
    #pragma unroll
    for (int j = 0; j < 3; ++j)
      if ((unsigned)(y + i - 1) < 56u && (unsigned)(x + j - 1) < 56u)
        vm |= 1 << (i * 3 + j);

  const int lr = lane & 15;
  const int lk = (lane >> 4) << 4;
  const int swz = (lr & 7) << 4;

  floatx4 acc[2][4] = {};

  // gather 8 consecutive k (k0 = kbx*64 + q8) for row prow; per-lane decode
  auto gatherQ = [&](float (&av)[8], int kbx) {
    int k0 = kbx * 64 + q8;
    unsigned c0 = (unsigned)k0 / 9u;             // magic-mul
    int r0 = k0 - (int)c0 * 9;
    #pragma unroll
    for (int u = 0; u < 8; ++u) {
      int tt = r0 + u;
      int w9 = tt >= 9 ? 1 : 0;
      int ij = tt - w9 * 9;
      int c = (int)c0 + w9;
      int iy = (ij >= 3 ? 1 : 0) + (ij >= 6 ? 1 : 0);
      int soff = c * 3136 + ij + iy * 53 - 57;   // c*3136 + (ij/3)*56 + ij%3 - 57
      float v = 0.f;
      if ((vm >> ij) & 1)
        v = in[eidx0 + soff];
      av[u] = v;
    }
  };

  // in-wave reduce (8 lanes share a row: xor 1,2,4) + quantize + As write
  auto quantWrite = [&](float (&av)[8], int sp, int half) {
    float mx = 0.f;
    #pragma unroll
    for (int u = 0; u < 8; ++u) mx = fmaxf(mx, fabsf(av[u]));
    mx = fmaxf(mx, __shfl_xor(mx, 1));
    mx = fmaxf(mx, __shfl_xor(mx, 2));
    mx = fmaxf(mx, __shfl_xor(mx, 4));
    short8 aq = (short8)0;
    unsigned mb = __builtin_bit_cast(unsigned, mx);   // nonneg: bits>0 <=> mx>0
    if (mb) {
      int e = (int)(mb >> 23) - 127;
      if (e < -126) e = -126;
      float inv = make_pow2(6 - e);
      float s   = make_pow2(e - 6);
      #pragma unroll
      for (int u = 0; u < 8; ++u) {
        float r = fminf(rintf(av[u] * inv), 127.f);   // lower clamp never binds
        float q = r * s;
        aq[u] = (short)(unsigned short)(__builtin_bit_cast(unsigned, q) >> 16);
      }
    }
    char* arow = (char*)As[sp][half] + prow * 128;
    *(short8*)(arow + (((lane & 7) ^ (lane >> 3)) << 4)) = aq;  // chunk ^ (row&7)
  };

  auto loadB = [&](bf16x8 (&bq)[2][4], int kb) {   // 8x global dwordx4 (L2-resident)
    #pragma unroll
    for (int ks = 0; ks < 2; ++ks)
      #pragma unroll
      for (int fn = 0; fn < 4; ++fn) {
        int ct = wn * 4 + fn;
        bq[ks][fn] = __builtin_bit_cast(bf16x8, *(const short8*)(
            (const char*)qw + ((size_t)((ct * 18 + kb) * 2 + ks) * 64 + lane) * 16));
      }
  };

  auto mfmaK = [&](bf16x8 (&bq)[2][4], int sp, int half) {
    const char* abase = (const char*)As[sp][half] + wm * 32 * 128;
    __builtin_amdgcn_s_setprio(1);
    #pragma unroll
    for (int ks = 0; ks < 2; ++ks) {
      const int kbyte = (ks * 64 + lk) ^ swz;
      #pragma unroll
      for (int fm = 0; fm < 2; ++fm) {
        bf16x8 af = __builtin_bit_cast(bf16x8,
            *(const short8*)(abase + (fm * 16 + lr) * 128 + kbyte));
        #pragma unroll
        for (int fn = 0; fn < 4; ++fn)
          acc[fm][fn] = __builtin_amdgcn_mfma_f32_16x16x32_bf16(bq[ks][fn], af, acc[fm][fn], 0, 0, 0);
      }
    }
    __builtin_amdgcn_s_setprio(0);
  };

  float avP[8], avQ[8];

  // ---- prologue: produce kb 0..3 into superphase slots 0,1 ----
  gatherQ(avP, 0); gatherQ(avQ, 1);
  quantWrite(avP, 0, 0); quantWrite(avQ, 0, 1);
  gatherQ(avP, 2); gatherQ(avQ, 3);
  quantWrite(avP, 1, 0); quantWrite(avQ, 1, 1);
  barrier_lgkm();

  // Superphase p: read slot rs=p%3 (kb 2p,2p+1); produce kb 2p+4,2p+5 into ws=(p+2)%3.
  auto phase = [&](int p, int rs, int ws) {
    bf16x8 bq[2][4];
    loadB(bq, 2 * p);                    // L2 latency covered by gather decode below
    const bool prod = 2 * p + 4 < 18;
    if (prod) { gatherQ(avP, 2 * p + 4); gatherQ(avQ, 2 * p + 5); }
    mfmaK(bq, rs, 0);
    loadB(bq, 2 * p + 1);
    mfmaK(bq, rs, 1);
    if (prod) { quantWrite(avP, ws, 0); quantWrite(avQ, ws, 1); }  // gathers covered by mfma
    barrier_lgkm();
  };

  #pragma unroll 1
  for (int p = 0; p < 9; p += 3) {
    phase(p,     0, 2);
    phase(p + 1, 1, 0);
    phase(p + 2, 2, 1);
  }

  // ---- epilogue: D[co][pix]; 3136 = 49*64 so the 64-row tile is one image ----
  const unsigned ni = (mt * 64u) / 3136u;
  const unsigned pp0 = mt * 64u - ni * 3136u;
  float* obase = out + (size_t)ni * 802816u + pp0;
  const int cg = (lane >> 4) << 2;
  #pragma unroll
  for (int fn = 0; fn < 4; ++fn) {
    floatx4 bv = *(const floatx4*)&bias[wn * 64 + fn * 16 + cg];
    #pragma unroll
    for (int r = 0; r < 4; ++r) {
      int co = wn * 64 + fn * 16 + cg + r;
      float* orow = obase + (size_t)co * 3136u;
      #pragma unroll
      for (int fm = 0; fm < 2; ++fm)
        orow[wm * 32 + fm * 16 + lr] = acc[fm][fn][r] + bv[r];
    }
  }
}

extern "C" void kernel_launch(void* const* d_in, const int* in_sizes, int n_in,
                              void* d_out, int out_size, void* d_ws, size_t ws_size,
                              hipStream_t stream) {
  const float* in   = (const float*)d_in[0];
  const float* w    = (const float*)d_in[1];
  const float* bias = (const float*)d_in[2];
  float* out = (float*)d_out;
  unsigned short* qw = (unsigned short*)d_ws;   // 16*18*1024 ushort = 589824 B

  quant_w_kernel<<<288, 64, 0, stream>>>(w, qw);
  conv_bfp_kernel<<<1568, 512, 0, stream>>>(in, qw, bias, out);
}

// Round 12
// 158.652 us; speedup vs baseline: 1.0482x; 1.0482x over previous
//
#include <hip/hip_runtime.h>

typedef short short8 __attribute__((ext_vector_type(8)));
typedef __bf16 bf16x8 __attribute__((ext_vector_type(8)));
typedef float floatx4 __attribute__((ext_vector_type(4)));

__device__ __forceinline__ float make_pow2(int e) {
  return __builtin_bit_cast(float, (unsigned)((e + 127) << 23));
}

// Raw barrier: drains LDS ops only (global loads are all to-register; ordinary
// register dependencies handle their waits).
__device__ __forceinline__ void barrier_lgkm() {
  asm volatile("s_waitcnt lgkmcnt(0)" ::: "memory");
  __builtin_amdgcn_sched_barrier(0);
  __builtin_amdgcn_s_barrier();
  asm volatile("" ::: "memory");
  __builtin_amdgcn_sched_barrier(0);
}

// ---------------- Phase 1: quantize weights -> bf16 FRAGMENT-ORDER blob ----------------
// Blob layout: [ct(16)][kb(18)][ks(2)][lane(64)][j(8)] bf16 = mfma src0 frag order.
__global__ void quant_w_kernel(const float* __restrict__ w, unsigned short* __restrict__ qw) {
  int b = blockIdx.x;                 // 0..287
  int ct = b / 18, kb = b - ct * 18;
  int L = threadIdx.x;                // 0..63
  int co = ct * 16 + (L & 15);
  int kq = L >> 4;                    // 0..3
  const float* wr = w + co * 1152 + kb * 64 + kq * 8;
  float v[16];
  float a = 0.f;
  #pragma unroll
  for (int ks = 0; ks < 2; ++ks)
    #pragma unroll
    for (int j = 0; j < 8; ++j) {
      float t = wr[ks * 32 + j];
      v[ks * 8 + j] = t;
      a = fmaxf(a, fabsf(t));
    }
  a = fmaxf(a, __shfl_xor(a, 16));
  a = fmaxf(a, __shfl_xor(a, 32));
  short8 q0 = (short8)0, q1 = (short8)0;
  if (a > 0.f) {
    int e = (int)((__builtin_bit_cast(unsigned, a) >> 23) & 0xffu) - 127;
    if (e < -126) e = -126;
    float inv = make_pow2(6 - e);
    float s   = make_pow2(e - 6);
    #pragma unroll
    for (int u = 0; u < 16; ++u) {
      float r = rintf(v[u] * inv);
      r = fminf(fmaxf(r, -128.f), 127.f);
      float qq = r * s;
      unsigned short hb = (unsigned short)(__builtin_bit_cast(unsigned, qq) >> 16);
      if (u < 8) q0[u] = (short)hb; else q1[u - 8] = (short)hb;
    }
  }
  unsigned short* dst = qw + (size_t)(ct * 18 + kb) * 1024;
  *(short8*)(dst + L * 8) = q0;          // ks = 0
  *(short8*)(dst + 512 + L * 8) = q1;    // ks = 1
}

// ---------------- Phase 2: fused im2col + BFP-quantize + GEMM ----------------
// M=100352, N=256, K=1152. BM=64, BN=256. 512 thr = 8 waves; wave owns a 32-col
// N-slab (acc[4][2]). r8 structure (scalarized gather, pmax LDS reduce, 2-kb
// superphase with one lgkm barrier, 4-slot As/pmax rotation), now PERSISTENT:
// 784 blocks x 2 tiles each (1568 = 2*784 exactly) so ~3-4 blocks stay resident
// per CU for the whole kernel; pipeline prologue amortized; no launch ramp.
__global__ __launch_bounds__(512, 4) void conv_bfp_kernel(
    const float* __restrict__ in, const unsigned short* __restrict__ qw,
    const float* __restrict__ bias, float* __restrict__ out) {
  __shared__ unsigned short As[4][64 * 64];    // 32 KB, 4-slot rotation
  __shared__ float pmax[4][8][64];             // 8 KB  [slot][wave][row]

  const int bid = blockIdx.x;
  const int t = threadIdx.x;
  const int lane = t & 63;
  const int wave = __builtin_amdgcn_readfirstlane(t >> 6);

  const int lr = lane & 15;
  const int lk = (lane >> 4) << 4;
  const int swz = (lr & 7) << 4;

  #pragma unroll 1
  for (int rep = 0; rep < 2; ++rep) {
    const int tile = bid + rep * 784;
    const int mt = (tile & 7) * 196 + (tile >> 3);   // XCD-chunked swizzle (1568 = 8*196)

    // ---- pixel geometry (A row = lane) ----
    const unsigned m = mt * 64u + lane;
    const unsigned nimg = m / 3136u;
    const unsigned py = m - nimg * 3136u;
    const int y = (int)(py / 56u);
    const int x = (int)(py - (unsigned)y * 56u);
    const int vbase = (int)((nimg * 401408u + (unsigned)y * 56u + (unsigned)x) * 4u);
    int vm = 0;
    #pragma unroll
    for (int i = 0; i < 3; ++i)
      #pragma unroll
      for (int j = 0; j < 3; ++j)
        if ((unsigned)(y + i - 1) < 56u && (unsigned)(x + j - 1) < 56u)
          vm |= 1 << (i * 3 + j);

    floatx4 acc[4][2] = {};

    auto gather = [&](float (&av)[8], int kb) {
      const int k0 = __builtin_amdgcn_readfirstlane(kb * 64 + wave * 8);
      #pragma unroll
      for (int u = 0; u < 8; ++u) {
        int k = k0 + u;                          // scalar
        int c = (int)((unsigned)k / 9u);
        int ij = k - c * 9;
        int soff = c * 3136 + (ij / 3) * 56 + (ij % 3) - 57;
        const char* pk = (const char*)in + (ptrdiff_t)soff * 4;
        float v = 0.f;
        if ((vm >> ij) & 1)
          v = *(const float*)(pk + vbase);       // global_load_dword v, vbase, s[pk]
        av[u] = v;
      }
    };

    auto loadB = [&](bf16x8 (&bq)[2][2], int kb) {   // [ks][fn], 4x global dwordx4
      #pragma unroll
      for (int ks = 0; ks < 2; ++ks)
        #pragma unroll
        for (int fn = 0; fn < 2; ++fn) {
          int ct = wave * 2 + fn;
          bq[ks][fn] = __builtin_bit_cast(bf16x8, *(const short8*)(
              (const char*)qw + ((size_t)((ct * 18 + kb) * 2 + ks) * 64 + lane) * 16));
        }
    };

    auto lmax_store = [&](float (&av)[8], int kb) {
      float lm = 0.f;
      #pragma unroll
      for (int u = 0; u < 8; ++u) lm = fmaxf(lm, fabsf(av[u]));
      pmax[kb & 3][wave][lane] = lm;
    };

    auto quantWrite = [&](float (&av)[8], int kb) {  // -> As[kb&3], reads pmax[kb&3]
      const float* pb = &pmax[kb & 3][0][lane];
      float ma = 0.f;
      #pragma unroll
      for (int j = 0; j < 8; ++j) ma = fmaxf(ma, pb[j * 64]);
      short8 aq = (short8)0;
      if (ma > 0.f) {
        int e = (int)((__builtin_bit_cast(unsigned, ma) >> 23) & 0xffu) - 127;
        if (e < -126) e = -126;
        float inv = make_pow2(6 - e);
        float s   = make_pow2(e - 6);
        #pragma unroll
        for (int u = 0; u < 8; ++u) {
          float r = fminf(rintf(av[u] * inv), 127.f);  // lower clamp never binds
          float q = r * s;
          aq[u] = (short)(unsigned short)(__builtin_bit_cast(unsigned, q) >> 16);
        }
      }
      char* arow = (char*)As[kb & 3] + lane * 128;
      *(short8*)(arow + ((wave * 16) ^ ((lane & 7) << 4))) = aq;
    };

    auto mfmaBlk = [&](bf16x8 (&bq)[2][2], int kb) {  // reads As[kb&3]
      const char* abase = (const char*)As[kb & 3];
      __builtin_amdgcn_s_setprio(1);
      #pragma unroll
      for (int ks = 0; ks < 2; ++ks) {
        const int kbyte = (ks * 64 + lk) ^ swz;
        #pragma unroll
        for (int fm = 0; fm < 4; ++fm) {
          bf16x8 af = __builtin_bit_cast(bf16x8,
              *(const short8*)(abase + (fm * 16 + lr) * 128 + kbyte));
          #pragma unroll
          for (int fn = 0; fn < 2; ++fn)
            acc[fm][fn] = __builtin_amdgcn_mfma_f32_16x16x32_bf16(bq[ks][fn], af, acc[fm][fn], 0, 0, 0);
        }
      }
      __builtin_amdgcn_s_setprio(0);
    };

    // Superphase: one barrier per 2 kb. q0/q1 hold gathered kb+2/kb+3;
    // g0/g1 receive kb+4/kb+5.
    auto superp = [&](int kb, float (&q0)[8], float (&q1)[8],
                      float (&g0)[8], float (&g1)[8]) {
      barrier_lgkm();              // As[kb&3],[kb+1&3] + pmax[(kb+2)&3],[(kb+3)&3] visible
      bf16x8 bq[2][2], bq2[2][2];
      loadB(bq, kb);
      if (kb + 2 < 18) { quantWrite(q0, kb + 2); quantWrite(q1, kb + 3); }
      if (kb + 4 < 18) { gather(g0, kb + 4); gather(g1, kb + 5); }
      loadB(bq2, kb + 1);          // covered by mfma(kb)
      mfmaBlk(bq, kb);
      if (kb + 4 < 18) { lmax_store(g0, kb + 4); lmax_store(g1, kb + 5); }
      mfmaBlk(bq2, kb + 1);
    };

    float gA[8], gB[8], gC[8], gD[8];

    // ---- prologue: fill pmax 0..3 and As 0,1 ----
    // (pmax slots 0..3 are not read by any straggler from the previous tile, and
    //  the barrier below also separates As[0],As[1] writes from the previous
    //  tile's last MFMA reads — this barrier is the tile seam.)
    gather(gA, 0); gather(gB, 1); gather(gC, 2); gather(gD, 3);
    lmax_store(gA, 0); lmax_store(gB, 1); lmax_store(gC, 2); lmax_store(gD, 3);
    barrier_lgkm();                // pmax 0..3 visible; prev-tile As reads done
    quantWrite(gA, 0); quantWrite(gB, 1);   // As0, As1  (gA,gB free)

    #pragma unroll 1
    for (int kb = 0; kb < 16; kb += 4) {
      superp(kb,     gC, gD, gA, gB);   // quant kb+2,kb+3; gather kb+4,kb+5
      superp(kb + 2, gA, gB, gC, gD);
    }
    superp(16, gC, gD, gA, gB);         // mfma 16,17 only (guards skip the rest)

    // ---- epilogue: D[co][pix]; 3136 = 49*64 so the 64-row tile is one image ----
    const unsigned ni = (mt * 64u) / 3136u;
    const unsigned pp0 = mt * 64u - ni * 3136u;
    float* obase = out + (size_t)ni * 802816u + pp0;
    const int cg = (lane >> 4) << 2;
    #pragma unroll
    for (int fn = 0; fn < 2; ++fn) {
      floatx4 bv = *(const floatx4*)&bias[wave * 32 + fn * 16 + cg];
      #pragma unroll
      for (int r = 0; r < 4; ++r) {
        int co = wave * 32 + fn * 16 + cg + r;
        float* orow = obase + (size_t)co * 3136u;
        #pragma unroll
        for (int fm = 0; fm < 4; ++fm)
          orow[fm * 16 + lr] = acc[fm][fn][r] + bv[r];
      }
    }
  }
}

extern "C" void kernel_launch(void* const* d_in, const int* in_sizes, int n_in,
                              void* d_out, int out_size, void* d_ws, size_t ws_size,
                              hipStream_t stream) {
  const float* in   = (const float*)d_in[0];
  const float* w    = (const float*)d_in[1];
  const float* bias = (const float*)d_in[2];
  float* out = (float*)d_out;
  unsigned short* qw = (unsigned short*)d_ws;   // 16*18*1024 ushort = 589824 B

  quant_w_kernel<<<288, 64, 0, stream>>>(w, qw);
  conv_bfp_kernel<<<784, 512, 0, stream>>>(in, qw, bias, out);
}